// Round 3
// baseline (401.347 us; speedup 1.0000x reference)
//
#include <hip/hip_runtime.h>
#include <hip/hip_bf16.h>

typedef unsigned short u16;
typedef unsigned int u32;

#define LRELU_SLOPE 0.2f
#define EPS_LN 1e-5f
#define EPS_SM 1e-16f

__device__ __forceinline__ float bflo(u32 u){ union{u32 i; float f;} x; x.i = u<<16; return x.f; }
__device__ __forceinline__ float bfhi(u32 u){ union{u32 i; float f;} x; x.i = u & 0xffff0000u; return x.f; }
__device__ __forceinline__ u16 f2bf(float f){
  union{float f; u32 i;} x; x.f=f; u32 i=x.i;
  u32 r = (i + 0x7fffu + ((i>>16)&1u))>>16; return (u16)r;
}
__device__ __forceinline__ u32 pack2(float a, float b){ return (u32)f2bf(a) | ((u32)f2bf(b)<<16); }
__device__ __forceinline__ float lrelu(float x){ return x > 0.f ? x : LRELU_SLOPE*x; }

__device__ __forceinline__ float wsum(float v){
  #pragma unroll
  for(int o=32;o>0;o>>=1) v += __shfl_xor(v,o,64);
  return v;
}
__device__ __forceinline__ float wmax(float v){
  #pragma unroll
  for(int o=32;o>0;o>>=1) v = fmaxf(v, __shfl_xor(v,o,64));
  return v;
}

// ---------------- LN1: xt = LayerNorm(x) (fp32 out) ----------------
__global__ __launch_bounds__(256) void ln1_kernel(const float* __restrict__ x,
    const float* __restrict__ g, const float* __restrict__ b,
    float* __restrict__ xt, int n){
  int row  = blockIdx.x*4 + (threadIdx.x>>6);
  int lane = threadIdx.x & 63;
  if(row >= n) return;
  float2 xv = ((const float2*)(x + (size_t)row*128))[lane];
  float v0 = xv.x, v1 = xv.y;
  float mean = wsum(v0+v1) * (1.f/128.f);
  float d0 = v0-mean, d1 = v1-mean;
  float var = wsum(d0*d0 + d1*d1) * (1.f/128.f);
  float rstd = rsqrtf(var + EPS_LN);
  float2 gv = ((const float2*)g)[lane], bv = ((const float2*)b)[lane];
  float o0 = d0*rstd*gv.x + bv.x;
  float o1 = d1*rstd*gv.y + bv.y;
  ((float2*)(xt + (size_t)row*128))[lane] = make_float2(o0, o1);
}

// ---------------- GEMM: h = xt @ W (bf16 out) + a_src/a_dst epilogue ----------------
__global__ __launch_bounds__(256) void gemm_kernel(const float* __restrict__ xt,
    const float* __restrict__ W, const float* __restrict__ att_src, const float* __restrict__ att_dst,
    u16* __restrict__ h, float* __restrict__ a_src, float* __restrict__ a_dst, int n){
  __shared__ u16 Ws[128*128];     // 32 KB, row-major W[k][j], bf16-converted
  __shared__ float Xs[32][129];   // +1 pad: kills bank conflicts on column reads
  __shared__ float asp[32][4], adp[32][4];
  int tid = threadIdx.x;
  int r0  = blockIdx.x*32;
  for(int i=tid;i<4096;i+=256){   // 16384 floats as 4096 float4s -> bf16 LDS
    float4 w = ((const float4*)W)[i];
    ((u32*)Ws)[i*2  ] = pack2(w.x, w.y);
    ((u32*)Ws)[i*2+1] = pack2(w.z, w.w);
  }
  for(int i=tid;i<4096;i+=256){
    int r=i>>7, c=i&127; int gr=r0+r;
    Xs[r][c] = (gr<n) ? xt[(size_t)gr*128+c] : 0.f;
  }
  if(tid<128){ asp[tid>>2][tid&3]=0.f; adp[tid>>2][tid&3]=0.f; }
  __syncthreads();

  int cg = tid & 15, rg = tid >> 4;   // cols 8*cg..8*cg+7, rows 2*rg..2*rg+1
  float acc0[8]={}, acc1[8]={};
  for(int k=0;k<128;k++){
    uint4 wq = ((const uint4*)(Ws + k*128))[cg];
    float w[8];
    w[0]=bflo(wq.x); w[1]=bfhi(wq.x); w[2]=bflo(wq.y); w[3]=bfhi(wq.y);
    w[4]=bflo(wq.z); w[5]=bfhi(wq.z); w[6]=bflo(wq.w); w[7]=bfhi(wq.w);
    float x0 = Xs[2*rg][k], x1 = Xs[2*rg+1][k];
    #pragma unroll
    for(int c=0;c<8;c++){ acc0[c]=fmaf(x0,w[c],acc0[c]); acc1[c]=fmaf(x1,w[c],acc1[c]); }
  }
  // per-head attention logit partials (8 cols all in one head: head = cg>>2)
  int head = cg>>2, coff = (cg&3)*8;
  float as0=0,as1=0,ad0=0,ad1=0;
  #pragma unroll
  for(int c=0;c<8;c++){
    float av = att_src[head*32+coff+c];
    float dv = att_dst[head*32+coff+c];
    as0=fmaf(acc0[c],av,as0); as1=fmaf(acc1[c],av,as1);
    ad0=fmaf(acc0[c],dv,ad0); ad1=fmaf(acc1[c],dv,ad1);
  }
  atomicAdd(&asp[2*rg  ][head], as0); atomicAdd(&asp[2*rg+1][head], as1);
  atomicAdd(&adp[2*rg  ][head], ad0); atomicAdd(&adp[2*rg+1][head], ad1);

  int grow0 = r0 + 2*rg;
  if(grow0 < n){
    uint4 o; o.x=pack2(acc0[0],acc0[1]); o.y=pack2(acc0[2],acc0[3]);
             o.z=pack2(acc0[4],acc0[5]); o.w=pack2(acc0[6],acc0[7]);
    ((uint4*)(h + (size_t)grow0*128))[cg] = o;
  }
  if(grow0+1 < n){
    uint4 o; o.x=pack2(acc1[0],acc1[1]); o.y=pack2(acc1[2],acc1[3]);
             o.z=pack2(acc1[4],acc1[5]); o.w=pack2(acc1[6],acc1[7]);
    ((uint4*)(h + (size_t)(grow0+1)*128))[cg] = o;
  }
  __syncthreads();
  if(tid < 128){
    int r = tid>>2, hd = tid&3; int gr = r0+r;
    if(gr<n){ a_src[gr*4+hd]=asp[r][hd]; a_dst[gr*4+hd]=adp[r][hd]; }
  }
}

// ---------------- CSR build ----------------
__global__ void zero_kernel(int* p, int n){
  int i = blockIdx.x*blockDim.x + threadIdx.x; if(i<n) p[i]=0;
}
__global__ void hist_kernel(const int* __restrict__ dst, int* __restrict__ deg, int E){
  int e = blockIdx.x*blockDim.x + threadIdx.x; if(e<E) atomicAdd(&deg[dst[e]],1);
}
__global__ __launch_bounds__(1024) void scan_kernel(const int* __restrict__ deg,
    int* __restrict__ rowptr, int* __restrict__ cursor, int n){
  __shared__ int part[1024];
  int tid = threadIdx.x;
  int per = (n+1023)>>10;
  int s0 = tid*per, s1 = min(s0+per, n); if(s0>n) s0=n;
  int s=0; for(int i=s0;i<s1;i++) s+=deg[i];
  part[tid]=s; __syncthreads();
  int mys=s;
  for(int off=1;off<1024;off<<=1){
    int v = (tid>=off)? part[tid-off] : 0;
    __syncthreads();
    part[tid]+=v;
    __syncthreads();
  }
  int run = part[tid]-mys;
  for(int i=s0;i<s1;i++){ rowptr[i]=run; cursor[i]=run; run+=deg[i]; }
  if(tid==0) rowptr[n]=part[1023];
}
__global__ void scatter_kernel(const int* __restrict__ src, const int* __restrict__ dst,
    int* __restrict__ cursor, int* __restrict__ col, int E){
  int e = blockIdx.x*blockDim.x + threadIdx.x;
  if(e<E){ int d=dst[e]; int pos=atomicAdd(&cursor[d],1); col[pos]=src[e]; }
}

// ---------------- Aggregation: softmax + gather + bias + residual + LN2 ----------------
// One wave per dst node; lane covers channels 2*lane, 2*lane+1 (same head = lane>>4).
__global__ __launch_bounds__(256) void agg_kernel(const u16* __restrict__ h,
    const float* __restrict__ a_src, const float* __restrict__ a_dst,
    const int* __restrict__ rowptr, const int* __restrict__ col,
    const float* __restrict__ xt, const float* __restrict__ bias,
    const float* __restrict__ g2, const float* __restrict__ b2,
    float* __restrict__ out, int n){
  int d    = blockIdx.x*4 + (threadIdx.x>>6);
  int lane = threadIdx.x & 63;
  if(d >= n) return;
  float4 ad  = ((const float4*)a_dst)[d];
  float4 asd = ((const float4*)a_src)[d];
  float vs0 = lrelu(asd.x+ad.x), vs1 = lrelu(asd.y+ad.y);
  float vs2 = lrelu(asd.z+ad.z), vs3 = lrelu(asd.w+ad.w);
  int base = rowptr[d], deg = rowptr[d+1]-base;

  // pass 1: segment max (self-loop included)
  float m0=vs0,m1=vs1,m2=vs2,m3=vs3;
  for(int j0=0;j0<deg;j0+=64){
    int j=j0+lane;
    if(j<deg){
      int s = col[base+j];
      float4 a = ((const float4*)a_src)[s];
      m0=fmaxf(m0,lrelu(a.x+ad.x)); m1=fmaxf(m1,lrelu(a.y+ad.y));
      m2=fmaxf(m2,lrelu(a.z+ad.z)); m3=fmaxf(m3,lrelu(a.w+ad.w));
    }
  }
  m0=wmax(m0); m1=wmax(m1); m2=wmax(m2); m3=wmax(m3);

  float t0=expf(vs0-m0), t1=expf(vs1-m1), t2=expf(vs2-m2), t3=expf(vs3-m3);
  float p0=0,p1=0,p2=0,p3=0;
  float acc0=0, acc1=0;
  int hh = lane>>4;   // head of channels 2*lane, 2*lane+1

  // pass 2: exp + denominator partial + unnormalized weighted gather
  for(int j0=0;j0<deg;j0+=64){
    int j=j0+lane;
    int s=0; float e0=0,e1=0,e2=0,e3=0;
    if(j<deg){
      s = col[base+j];
      float4 a = ((const float4*)a_src)[s];
      e0=expf(lrelu(a.x+ad.x)-m0); e1=expf(lrelu(a.y+ad.y)-m1);
      e2=expf(lrelu(a.z+ad.z)-m2); e3=expf(lrelu(a.w+ad.w)-m3);
      p0+=e0; p1+=e1; p2+=e2; p3+=e3;
    }
    int cnt = min(64, deg-j0);
    for(int jj=0;jj<cnt;jj++){
      int   sj = __shfl(s, jj, 64);
      float b0 = __shfl(e0,jj,64), b1=__shfl(e1,jj,64), b2=__shfl(e2,jj,64), b3=__shfl(e3,jj,64);
      float al = hh<2 ? (hh==0? b0:b1) : (hh==2? b2:b3);
      u32 hw = ((const u32*)(h + (size_t)sj*128))[lane];
      acc0 = fmaf(al, bflo(hw), acc0);
      acc1 = fmaf(al, bfhi(hw), acc1);
    }
  }
  // self-loop message
  float es = hh<2 ? (hh==0? t0:t1) : (hh==2? t2:t3);
  u32 hwd = ((const u32*)(h + (size_t)d*128))[lane];
  acc0 = fmaf(es, bflo(hwd), acc0);
  acc1 = fmaf(es, bfhi(hwd), acc1);

  float S0 = wsum(p0)+t0, S1 = wsum(p1)+t1, S2 = wsum(p2)+t2, S3 = wsum(p3)+t3;
  float den = (hh<2 ? (hh==0? S0:S1) : (hh==2? S2:S3)) + EPS_SM;
  float inv = 1.f/den;
  acc0 *= inv; acc1 *= inv;

  // bias + residual + LN2
  float2 bb = ((const float2*)bias)[lane];
  float2 xr = ((const float2*)(xt + (size_t)d*128))[lane];
  float r0 = xr.x + acc0 + bb.x;
  float r1 = xr.y + acc1 + bb.y;
  float mean = wsum(r0+r1)*(1.f/128.f);
  float dd0=r0-mean, dd1=r1-mean;
  float var = wsum(dd0*dd0+dd1*dd1)*(1.f/128.f);
  float rstd = rsqrtf(var+EPS_LN);
  float2 gv=((const float2*)g2)[lane], bv=((const float2*)b2)[lane];
  float o0 = dd0*rstd*gv.x+bv.x;
  float o1 = dd1*rstd*gv.y+bv.y;
  ((float2*)(out + (size_t)d*128))[lane] = make_float2(o0, o1);
}

extern "C" void kernel_launch(void* const* d_in, const int* in_sizes, int n_in,
                              void* d_out, int out_size, void* d_ws, size_t ws_size,
                              hipStream_t stream) {
  const float* x     = (const float*)d_in[0];
  const int*   ei    = (const int*)d_in[1];
  const float* W     = (const float*)d_in[4];
  const float* att_s = (const float*)d_in[5];
  const float* att_d = (const float*)d_in[6];
  const float* bias  = (const float*)d_in[7];
  const float* g1    = (const float*)d_in[8];
  const float* b1    = (const float*)d_in[9];
  const float* g2    = (const float*)d_in[10];
  const float* b2    = (const float*)d_in[11];
  int n = in_sizes[0]/128;
  int E = in_sizes[1]/2;
  float* out = (float*)d_out;

  char* ws = (char*)d_ws;
  float* xt    = (float*)ws; ws += (size_t)n*128*4;
  u16*   h     = (u16*)ws;   ws += (size_t)n*128*2;
  float* a_src = (float*)ws; ws += (size_t)n*4*4;
  float* a_dst = (float*)ws; ws += (size_t)n*4*4;
  int* deg     = (int*)ws;   ws += (size_t)n*4;
  int* rowptr  = (int*)ws;   ws += (((size_t)(n+1)*4 + 255) & ~(size_t)255);
  int* cursor  = (int*)ws;   ws += (size_t)n*4;
  int* col     = (int*)ws;   ws += (size_t)E*4;

  dim3 b256(256);
  zero_kernel   <<<(n+255)/256, b256, 0, stream>>>(deg, n);
  ln1_kernel    <<<(n+3)/4,     b256, 0, stream>>>(x, g1, b1, xt, n);
  gemm_kernel   <<<(n+31)/32,   b256, 0, stream>>>(xt, W, att_s, att_d, h, a_src, a_dst, n);
  hist_kernel   <<<(E+255)/256, b256, 0, stream>>>(ei+E, deg, E);
  scan_kernel   <<<1, 1024, 0, stream>>>(deg, rowptr, cursor, n);
  scatter_kernel<<<(E+255)/256, b256, 0, stream>>>(ei, ei+E, cursor, col, E);
  agg_kernel    <<<(n+3)/4,     b256, 0, stream>>>(h, a_src, a_dst, rowptr, col, xt, bias, g2, b2, out, n);
}

// Round 4
// 300.734 us; speedup vs baseline: 1.3346x; 1.3346x over previous
//
#include <hip/hip_runtime.h>
#include <hip/hip_bf16.h>

typedef unsigned short u16;
typedef unsigned int u32;

#define LRELU_SLOPE 0.2f
#define EPS_LN 1e-5f
#define EPS_SM 1e-16f
#define SCAN_CHUNK 4096   // 256 threads x 16 elems

__device__ __forceinline__ float bflo(u32 u){ union{u32 i; float f;} x; x.i = u<<16; return x.f; }
__device__ __forceinline__ float bfhi(u32 u){ union{u32 i; float f;} x; x.i = u & 0xffff0000u; return x.f; }
__device__ __forceinline__ u16 f2bf(float f){
  union{float f; u32 i;} x; x.f=f; u32 i=x.i;
  u32 r = (i + 0x7fffu + ((i>>16)&1u))>>16; return (u16)r;
}
__device__ __forceinline__ u32 pack2(float a, float b){ return (u32)f2bf(a) | ((u32)f2bf(b)<<16); }
__device__ __forceinline__ float lrelu(float x){ return x > 0.f ? x : LRELU_SLOPE*x; }

__device__ __forceinline__ float wsum(float v){
  #pragma unroll
  for(int o=32;o>0;o>>=1) v += __shfl_xor(v,o,64);
  return v;
}
__device__ __forceinline__ float wmax(float v){
  #pragma unroll
  for(int o=32;o>0;o>>=1) v = fmaxf(v, __shfl_xor(v,o,64));
  return v;
}

// ---------------- LN1: xt = LayerNorm(x) (fp32 out) ----------------
__global__ __launch_bounds__(256) void ln1_kernel(const float* __restrict__ x,
    const float* __restrict__ g, const float* __restrict__ b,
    float* __restrict__ xt, int n){
  int row  = blockIdx.x*4 + (threadIdx.x>>6);
  int lane = threadIdx.x & 63;
  if(row >= n) return;
  float2 xv = ((const float2*)(x + (size_t)row*128))[lane];
  float v0 = xv.x, v1 = xv.y;
  float mean = wsum(v0+v1) * (1.f/128.f);
  float d0 = v0-mean, d1 = v1-mean;
  float var = wsum(d0*d0 + d1*d1) * (1.f/128.f);
  float rstd = rsqrtf(var + EPS_LN);
  float2 gv = ((const float2*)g)[lane], bv = ((const float2*)b)[lane];
  float o0 = d0*rstd*gv.x + bv.x;
  float o1 = d1*rstd*gv.y + bv.y;
  ((float2*)(xt + (size_t)row*128))[lane] = make_float2(o0, o1);
}

// ---------------- GEMM: h = xt @ W (bf16 out) + a_src/a_dst epilogue ----------------
__global__ __launch_bounds__(256) void gemm_kernel(const float* __restrict__ xt,
    const float* __restrict__ W, const float* __restrict__ att_src, const float* __restrict__ att_dst,
    u16* __restrict__ h, float* __restrict__ a_src, float* __restrict__ a_dst, int n){
  __shared__ u16 Ws[128*128];     // 32 KB, row-major W[k][j], bf16-converted
  __shared__ float Xs[32][129];   // +1 pad: kills bank conflicts on column reads
  __shared__ float asp[32][4], adp[32][4];
  int tid = threadIdx.x;
  int r0  = blockIdx.x*32;
  for(int i=tid;i<4096;i+=256){   // 16384 floats as 4096 float4s -> bf16 LDS
    float4 w = ((const float4*)W)[i];
    ((u32*)Ws)[i*2  ] = pack2(w.x, w.y);
    ((u32*)Ws)[i*2+1] = pack2(w.z, w.w);
  }
  for(int i=tid;i<4096;i+=256){
    int r=i>>7, c=i&127; int gr=r0+r;
    Xs[r][c] = (gr<n) ? xt[(size_t)gr*128+c] : 0.f;
  }
  if(tid<128){ asp[tid>>2][tid&3]=0.f; adp[tid>>2][tid&3]=0.f; }
  __syncthreads();

  int cg = tid & 15, rg = tid >> 4;   // cols 8*cg..8*cg+7, rows 2*rg..2*rg+1
  float acc0[8]={}, acc1[8]={};
  for(int k=0;k<128;k++){
    uint4 wq = ((const uint4*)(Ws + k*128))[cg];
    float w[8];
    w[0]=bflo(wq.x); w[1]=bfhi(wq.x); w[2]=bflo(wq.y); w[3]=bfhi(wq.y);
    w[4]=bflo(wq.z); w[5]=bfhi(wq.z); w[6]=bflo(wq.w); w[7]=bfhi(wq.w);
    float x0 = Xs[2*rg][k], x1 = Xs[2*rg+1][k];
    #pragma unroll
    for(int c=0;c<8;c++){ acc0[c]=fmaf(x0,w[c],acc0[c]); acc1[c]=fmaf(x1,w[c],acc1[c]); }
  }
  // per-head attention logit partials (8 cols all in one head: head = cg>>2)
  int head = cg>>2, coff = (cg&3)*8;
  float as0=0,as1=0,ad0=0,ad1=0;
  #pragma unroll
  for(int c=0;c<8;c++){
    float av = att_src[head*32+coff+c];
    float dv = att_dst[head*32+coff+c];
    as0=fmaf(acc0[c],av,as0); as1=fmaf(acc1[c],av,as1);
    ad0=fmaf(acc0[c],dv,ad0); ad1=fmaf(acc1[c],dv,ad1);
  }
  atomicAdd(&asp[2*rg  ][head], as0); atomicAdd(&asp[2*rg+1][head], as1);
  atomicAdd(&adp[2*rg  ][head], ad0); atomicAdd(&adp[2*rg+1][head], ad1);

  int grow0 = r0 + 2*rg;
  if(grow0 < n){
    uint4 o; o.x=pack2(acc0[0],acc0[1]); o.y=pack2(acc0[2],acc0[3]);
             o.z=pack2(acc0[4],acc0[5]); o.w=pack2(acc0[6],acc0[7]);
    ((uint4*)(h + (size_t)grow0*128))[cg] = o;
  }
  if(grow0+1 < n){
    uint4 o; o.x=pack2(acc1[0],acc1[1]); o.y=pack2(acc1[2],acc1[3]);
             o.z=pack2(acc1[4],acc1[5]); o.w=pack2(acc1[6],acc1[7]);
    ((uint4*)(h + (size_t)(grow0+1)*128))[cg] = o;
  }
  __syncthreads();
  if(tid < 128){
    int r = tid>>2, hd = tid&3; int gr = r0+r;
    if(gr<n){ a_src[gr*4+hd]=asp[r][hd]; a_dst[gr*4+hd]=adp[r][hd]; }
  }
}

// ---------------- CSR build ----------------
__global__ void zero_kernel(int* p, int n){
  int i = blockIdx.x*blockDim.x + threadIdx.x; if(i<n) p[i]=0;
}
__global__ void hist_kernel(const int* __restrict__ dst, int* __restrict__ deg, int E){
  int e = blockIdx.x*blockDim.x + threadIdx.x; if(e<E) atomicAdd(&deg[dst[e]],1);
}

// Phase A: per-chunk exclusive scan (256 thr x 16 elems), write chunk totals.
__global__ __launch_bounds__(256) void scanA_kernel(const int* __restrict__ deg,
    int* __restrict__ rowptr, int* __restrict__ bsum, int n){
  __shared__ int part[256];
  int tid = threadIdx.x;
  int base = blockIdx.x*SCAN_CHUNK + tid*16;
  int v[16]; int s=0;
  #pragma unroll
  for(int i=0;i<16;i++){ int idx=base+i; int xv=(idx<n)? deg[idx]:0; v[i]=s; s+=xv; }
  part[tid]=s; __syncthreads();
  int mys=s;
  for(int off=1;off<256;off<<=1){
    int t = (tid>=off)? part[tid-off] : 0;
    __syncthreads(); part[tid]+=t; __syncthreads();
  }
  int run = part[tid]-mys;
  #pragma unroll
  for(int i=0;i<16;i++){ int idx=base+i; if(idx<n) rowptr[idx]=v[i]+run; }
  if(tid==255) bsum[blockIdx.x]=part[255];
}
// Phase B: one wave exclusive-scans block totals (nb <= 64), writes rowptr[n].
__global__ __launch_bounds__(64) void scanB_kernel(int* __restrict__ bsum,
    int* __restrict__ rowptr, int nb, int n){
  int lane = threadIdx.x;
  int v = (lane<nb)? bsum[lane] : 0;
  int inc = v;
  #pragma unroll
  for(int o=1;o<64;o<<=1){ int t=__shfl_up(inc,o,64); if(lane>=o) inc+=t; }
  if(lane<nb) bsum[lane] = inc - v;           // exclusive
  if(lane==63) rowptr[n] = inc;               // total
}
// Phase C: add chunk offsets, init cursor.
__global__ __launch_bounds__(256) void scanC_kernel(int* __restrict__ rowptr,
    const int* __restrict__ bsum, int* __restrict__ cursor, int n){
  int idx = blockIdx.x*blockDim.x + threadIdx.x;
  if(idx<n){ int v = rowptr[idx] + bsum[idx/SCAN_CHUNK]; rowptr[idx]=v; cursor[idx]=v; }
}

__global__ void scatter_kernel(const int* __restrict__ src, const int* __restrict__ dst,
    int* __restrict__ cursor, int* __restrict__ col, int E){
  int e = blockIdx.x*blockDim.x + threadIdx.x;
  if(e<E){ int d=dst[e]; int pos=atomicAdd(&cursor[d],1); col[pos]=src[e]; }
}

// ---------------- Aggregation: softmax + gather + bias + residual + LN2 ----------------
// One wave per dst node; lane covers channels 2*lane, 2*lane+1 (same head = lane>>4).
__global__ __launch_bounds__(256) void agg_kernel(const u16* __restrict__ h,
    const float* __restrict__ a_src, const float* __restrict__ a_dst,
    const int* __restrict__ rowptr, const int* __restrict__ col,
    const float* __restrict__ xt, const float* __restrict__ bias,
    const float* __restrict__ g2, const float* __restrict__ b2,
    float* __restrict__ out, int n){
  int d    = blockIdx.x*4 + (threadIdx.x>>6);
  int lane = threadIdx.x & 63;
  if(d >= n) return;
  float4 ad  = ((const float4*)a_dst)[d];
  float4 asd = ((const float4*)a_src)[d];
  float vs0 = lrelu(asd.x+ad.x), vs1 = lrelu(asd.y+ad.y);
  float vs2 = lrelu(asd.z+ad.z), vs3 = lrelu(asd.w+ad.w);
  int base = rowptr[d], deg = rowptr[d+1]-base;

  // pass 1: segment max (self-loop included)
  float m0=vs0,m1=vs1,m2=vs2,m3=vs3;
  for(int j0=0;j0<deg;j0+=64){
    int j=j0+lane;
    if(j<deg){
      int s = col[base+j];
      float4 a = ((const float4*)a_src)[s];
      m0=fmaxf(m0,lrelu(a.x+ad.x)); m1=fmaxf(m1,lrelu(a.y+ad.y));
      m2=fmaxf(m2,lrelu(a.z+ad.z)); m3=fmaxf(m3,lrelu(a.w+ad.w));
    }
  }
  m0=wmax(m0); m1=wmax(m1); m2=wmax(m2); m3=wmax(m3);

  float t0=expf(vs0-m0), t1=expf(vs1-m1), t2=expf(vs2-m2), t3=expf(vs3-m3);
  float p0=0,p1=0,p2=0,p3=0;
  float acc0=0, acc1=0;
  int hh = lane>>4;   // head of channels 2*lane, 2*lane+1

  // pass 2: exp + denominator partial + unnormalized weighted gather
  for(int j0=0;j0<deg;j0+=64){
    int j=j0+lane;
    int s=0; float e0=0,e1=0,e2=0,e3=0;
    if(j<deg){
      s = col[base+j];
      float4 a = ((const float4*)a_src)[s];
      e0=expf(lrelu(a.x+ad.x)-m0); e1=expf(lrelu(a.y+ad.y)-m1);
      e2=expf(lrelu(a.z+ad.z)-m2); e3=expf(lrelu(a.w+ad.w)-m3);
      p0+=e0; p1+=e1; p2+=e2; p3+=e3;
    }
    int cnt = min(64, deg-j0);
    for(int jj=0;jj<cnt;jj++){
      int   sj = __shfl(s, jj, 64);
      float b0 = __shfl(e0,jj,64), b1=__shfl(e1,jj,64), b2=__shfl(e2,jj,64), b3=__shfl(e3,jj,64);
      float al = hh<2 ? (hh==0? b0:b1) : (hh==2? b2:b3);
      u32 hw = ((const u32*)(h + (size_t)sj*128))[lane];
      acc0 = fmaf(al, bflo(hw), acc0);
      acc1 = fmaf(al, bfhi(hw), acc1);
    }
  }
  // self-loop message
  float es = hh<2 ? (hh==0? t0:t1) : (hh==2? t2:t3);
  u32 hwd = ((const u32*)(h + (size_t)d*128))[lane];
  acc0 = fmaf(es, bflo(hwd), acc0);
  acc1 = fmaf(es, bfhi(hwd), acc1);

  float S0 = wsum(p0)+t0, S1 = wsum(p1)+t1, S2 = wsum(p2)+t2, S3 = wsum(p3)+t3;
  float den = (hh<2 ? (hh==0? S0:S1) : (hh==2? S2:S3)) + EPS_SM;
  float inv = 1.f/den;
  acc0 *= inv; acc1 *= inv;

  // bias + residual + LN2
  float2 bb = ((const float2*)bias)[lane];
  float2 xr = ((const float2*)(xt + (size_t)d*128))[lane];
  float r0 = xr.x + acc0 + bb.x;
  float r1 = xr.y + acc1 + bb.y;
  float mean = wsum(r0+r1)*(1.f/128.f);
  float dd0=r0-mean, dd1=r1-mean;
  float var = wsum(dd0*dd0+dd1*dd1)*(1.f/128.f);
  float rstd = rsqrtf(var+EPS_LN);
  float2 gv=((const float2*)g2)[lane], bv=((const float2*)b2)[lane];
  float o0 = dd0*rstd*gv.x+bv.x;
  float o1 = dd1*rstd*gv.y+bv.y;
  ((float2*)(out + (size_t)d*128))[lane] = make_float2(o0, o1);
}

extern "C" void kernel_launch(void* const* d_in, const int* in_sizes, int n_in,
                              void* d_out, int out_size, void* d_ws, size_t ws_size,
                              hipStream_t stream) {
  const float* x     = (const float*)d_in[0];
  const int*   ei    = (const int*)d_in[1];
  const float* W     = (const float*)d_in[4];
  const float* att_s = (const float*)d_in[5];
  const float* att_d = (const float*)d_in[6];
  const float* bias  = (const float*)d_in[7];
  const float* g1    = (const float*)d_in[8];
  const float* b1    = (const float*)d_in[9];
  const float* g2    = (const float*)d_in[10];
  const float* b2    = (const float*)d_in[11];
  int n = in_sizes[0]/128;
  int E = in_sizes[1]/2;
  float* out = (float*)d_out;

  char* ws = (char*)d_ws;
  float* xt    = (float*)ws; ws += (size_t)n*128*4;
  u16*   h     = (u16*)ws;   ws += (size_t)n*128*2;
  float* a_src = (float*)ws; ws += (size_t)n*4*4;
  float* a_dst = (float*)ws; ws += (size_t)n*4*4;
  int* deg     = (int*)ws;   ws += (size_t)n*4;
  int* rowptr  = (int*)ws;   ws += (((size_t)(n+1)*4 + 255) & ~(size_t)255);
  int* cursor  = (int*)ws;   ws += (size_t)n*4;
  int* bsum    = (int*)ws;   ws += 256;
  int* col     = (int*)ws;   ws += (size_t)E*4;

  int nb = (n + SCAN_CHUNK - 1) / SCAN_CHUNK;   // 13 for n=50000 (<= 64 up to n=262144)

  dim3 b256(256);
  zero_kernel   <<<(n+255)/256, b256, 0, stream>>>(deg, n);
  ln1_kernel    <<<(n+3)/4,     b256, 0, stream>>>(x, g1, b1, xt, n);
  gemm_kernel   <<<(n+31)/32,   b256, 0, stream>>>(xt, W, att_s, att_d, h, a_src, a_dst, n);
  hist_kernel   <<<(E+255)/256, b256, 0, stream>>>(ei+E, deg, E);
  scanA_kernel  <<<nb,          b256, 0, stream>>>(deg, rowptr, bsum, n);
  scanB_kernel  <<<1,           64,   0, stream>>>(bsum, rowptr, nb, n);
  scanC_kernel  <<<(n+255)/256, b256, 0, stream>>>(rowptr, bsum, cursor, n);
  scatter_kernel<<<(E+255)/256, b256, 0, stream>>>(ei, ei+E, cursor, col, E);
  agg_kernel    <<<(n+3)/4,     b256, 0, stream>>>(h, a_src, a_dst, rowptr, col, xt, bias, g2, b2, out, n);
}

// Round 6
// 283.494 us; speedup vs baseline: 1.4157x; 1.0608x over previous
//
#include <hip/hip_runtime.h>
#include <hip/hip_bf16.h>

typedef unsigned short u16;
typedef unsigned int u32;

#define LRELU_SLOPE 0.2f
#define EPS_LN 1e-5f
#define EPS_SM 1e-16f
#define SCAN_CHUNK 4096   // 256 threads x 16 elems

__device__ __forceinline__ float bflo(u32 u){ union{u32 i; float f;} x; x.i = u<<16; return x.f; }
__device__ __forceinline__ float bfhi(u32 u){ union{u32 i; float f;} x; x.i = u & 0xffff0000u; return x.f; }
__device__ __forceinline__ u16 f2bf(float f){
  union{float f; u32 i;} x; x.f=f; u32 i=x.i;
  u32 r = (i + 0x7fffu + ((i>>16)&1u))>>16; return (u16)r;
}
__device__ __forceinline__ u32 pack2(float a, float b){ return (u32)f2bf(a) | ((u32)f2bf(b)<<16); }
__device__ __forceinline__ float lrelu(float x){ return x > 0.f ? x : LRELU_SLOPE*x; }

__device__ __forceinline__ float wsum(float v){
  #pragma unroll
  for(int o=32;o>0;o>>=1) v += __shfl_xor(v,o,64);
  return v;
}
__device__ __forceinline__ float wmax(float v){
  #pragma unroll
  for(int o=32;o>0;o>>=1) v = fmaxf(v, __shfl_xor(v,o,64));
  return v;
}

// ---------------- LN1: xt = LayerNorm(x) (fp32 out) ----------------
__global__ __launch_bounds__(256) void ln1_kernel(const float* __restrict__ x,
    const float* __restrict__ g, const float* __restrict__ b,
    float* __restrict__ xt, int n){
  int row  = blockIdx.x*4 + (threadIdx.x>>6);
  int lane = threadIdx.x & 63;
  if(row >= n) return;
  float2 xv = ((const float2*)(x + (size_t)row*128))[lane];
  float v0 = xv.x, v1 = xv.y;
  float mean = wsum(v0+v1) * (1.f/128.f);
  float d0 = v0-mean, d1 = v1-mean;
  float var = wsum(d0*d0 + d1*d1) * (1.f/128.f);
  float rstd = rsqrtf(var + EPS_LN);
  float2 gv = ((const float2*)g)[lane], bv = ((const float2*)b)[lane];
  float o0 = d0*rstd*gv.x + bv.x;
  float o1 = d1*rstd*gv.y + bv.y;
  ((float2*)(xt + (size_t)row*128))[lane] = make_float2(o0, o1);
}

// ---------------- GEMM: h = xt @ W (bf16 out) + a_src/a_dst epilogue ----------------
__global__ __launch_bounds__(256) void gemm_kernel(const float* __restrict__ xt,
    const float* __restrict__ W, const float* __restrict__ att_src, const float* __restrict__ att_dst,
    u16* __restrict__ h, float* __restrict__ a_src, float* __restrict__ a_dst, int n){
  __shared__ u16 Ws[128*128];     // 32 KB, row-major W[k][j], bf16-converted
  __shared__ float Xs[32][129];   // +1 pad: kills bank conflicts on column reads
  __shared__ float asp[32][4], adp[32][4];
  int tid = threadIdx.x;
  int r0  = blockIdx.x*32;
  for(int i=tid;i<4096;i+=256){   // 16384 floats as 4096 float4s -> bf16 LDS
    float4 w = ((const float4*)W)[i];
    ((u32*)Ws)[i*2  ] = pack2(w.x, w.y);
    ((u32*)Ws)[i*2+1] = pack2(w.z, w.w);
  }
  for(int i=tid;i<4096;i+=256){
    int r=i>>7, c=i&127; int gr=r0+r;
    Xs[r][c] = (gr<n) ? xt[(size_t)gr*128+c] : 0.f;
  }
  if(tid<128){ asp[tid>>2][tid&3]=0.f; adp[tid>>2][tid&3]=0.f; }
  __syncthreads();

  int cg = tid & 15, rg = tid >> 4;   // cols 8*cg..8*cg+7, rows 2*rg..2*rg+1
  float acc0[8]={}, acc1[8]={};
  for(int k=0;k<128;k++){
    uint4 wq = ((const uint4*)(Ws + k*128))[cg];
    float w[8];
    w[0]=bflo(wq.x); w[1]=bfhi(wq.x); w[2]=bflo(wq.y); w[3]=bfhi(wq.y);
    w[4]=bflo(wq.z); w[5]=bfhi(wq.z); w[6]=bflo(wq.w); w[7]=bfhi(wq.w);
    float x0 = Xs[2*rg][k], x1 = Xs[2*rg+1][k];
    #pragma unroll
    for(int c=0;c<8;c++){ acc0[c]=fmaf(x0,w[c],acc0[c]); acc1[c]=fmaf(x1,w[c],acc1[c]); }
  }
  int head = cg>>2, coff = (cg&3)*8;
  float as0=0,as1=0,ad0=0,ad1=0;
  #pragma unroll
  for(int c=0;c<8;c++){
    float av = att_src[head*32+coff+c];
    float dv = att_dst[head*32+coff+c];
    as0=fmaf(acc0[c],av,as0); as1=fmaf(acc1[c],av,as1);
    ad0=fmaf(acc0[c],dv,ad0); ad1=fmaf(acc1[c],dv,ad1);
  }
  atomicAdd(&asp[2*rg  ][head], as0); atomicAdd(&asp[2*rg+1][head], as1);
  atomicAdd(&adp[2*rg  ][head], ad0); atomicAdd(&adp[2*rg+1][head], ad1);

  int grow0 = r0 + 2*rg;
  if(grow0 < n){
    uint4 o; o.x=pack2(acc0[0],acc0[1]); o.y=pack2(acc0[2],acc0[3]);
             o.z=pack2(acc0[4],acc0[5]); o.w=pack2(acc0[6],acc0[7]);
    ((uint4*)(h + (size_t)grow0*128))[cg] = o;
  }
  if(grow0+1 < n){
    uint4 o; o.x=pack2(acc1[0],acc1[1]); o.y=pack2(acc1[2],acc1[3]);
             o.z=pack2(acc1[4],acc1[5]); o.w=pack2(acc1[6],acc1[7]);
    ((uint4*)(h + (size_t)(grow0+1)*128))[cg] = o;
  }
  __syncthreads();
  if(tid < 128){
    int r = tid>>2, hd = tid&3; int gr = r0+r;
    if(gr<n){ a_src[gr*4+hd]=asp[r][hd]; a_dst[gr*4+hd]=adp[r][hd]; }
  }
}

// ---------------- CSR build ----------------
__global__ void zero_kernel(int* p, int n){
  int i = blockIdx.x*blockDim.x + threadIdx.x; if(i<n) p[i]=0;
}
__global__ void hist_kernel(const int* __restrict__ dst, int* __restrict__ deg, int E){
  int e = blockIdx.x*blockDim.x + threadIdx.x; if(e<E) atomicAdd(&deg[dst[e]],1);
}
__global__ __launch_bounds__(256) void scanA_kernel(const int* __restrict__ deg,
    int* __restrict__ rowptr, int* __restrict__ bsum, int n){
  __shared__ int part[256];
  int tid = threadIdx.x;
  int base = blockIdx.x*SCAN_CHUNK + tid*16;
  int v[16]; int s=0;
  #pragma unroll
  for(int i=0;i<16;i++){ int idx=base+i; int xv=(idx<n)? deg[idx]:0; v[i]=s; s+=xv; }
  part[tid]=s; __syncthreads();
  int mys=s;
  for(int off=1;off<256;off<<=1){
    int t = (tid>=off)? part[tid-off] : 0;
    __syncthreads(); part[tid]+=t; __syncthreads();
  }
  int run = part[tid]-mys;
  #pragma unroll
  for(int i=0;i<16;i++){ int idx=base+i; if(idx<n) rowptr[idx]=v[i]+run; }
  if(tid==255) bsum[blockIdx.x]=part[255];
}
__global__ __launch_bounds__(64) void scanB_kernel(int* __restrict__ bsum,
    int* __restrict__ rowptr, int nb, int n){
  int lane = threadIdx.x;
  int v = (lane<nb)? bsum[lane] : 0;
  int inc = v;
  #pragma unroll
  for(int o=1;o<64;o<<=1){ int t=__shfl_up(inc,o,64); if(lane>=o) inc+=t; }
  if(lane<nb) bsum[lane] = inc - v;
  if(lane==63) rowptr[n] = inc;
}
__global__ __launch_bounds__(256) void scanC_kernel(int* __restrict__ rowptr,
    const int* __restrict__ bsum, int* __restrict__ cursor, int n){
  int idx = blockIdx.x*blockDim.x + threadIdx.x;
  if(idx<n){ int v = rowptr[idx] + bsum[idx/SCAN_CHUNK]; rowptr[idx]=v; cursor[idx]=v; }
}
__global__ void scatter_kernel(const int* __restrict__ src, const int* __restrict__ dst,
    int* __restrict__ cursor, int* __restrict__ col, int E){
  int e = blockIdx.x*blockDim.x + threadIdx.x;
  if(e<E){ int d=dst[e]; int pos=atomicAdd(&cursor[d],1); col[pos]=src[e]; }
}

// ---------------- Aggregation: softmax + gather + bias + residual + LN2 ----------------
// One wave per dst. cl=lane&15 owns 8 channels (dwordx4 of bf16 h, head hc=cl>>2);
// q=lane>>4 owns edge it*4+q -> 4 edges per iteration, 1KB/wave gather instr.
__global__ __launch_bounds__(256) void agg_kernel(const u16* __restrict__ h,
    const float* __restrict__ a_src, const float* __restrict__ a_dst,
    const int* __restrict__ rowptr, const int* __restrict__ col,
    const float* __restrict__ xt, const float* __restrict__ bias,
    const float* __restrict__ g2, const float* __restrict__ b2,
    float* __restrict__ out, int n){
  int d    = blockIdx.x*4 + (threadIdx.x>>6);
  int lane = threadIdx.x & 63;
  if(d >= n) return;
  int q = lane>>4, cl = lane&15, hc = cl>>2;   // head of channels 8*cl..8*cl+7
  float4 ad  = ((const float4*)a_dst)[d];
  float4 asd = ((const float4*)a_src)[d];
  float vs0 = lrelu(asd.x+ad.x), vs1 = lrelu(asd.y+ad.y);
  float vs2 = lrelu(asd.z+ad.z), vs3 = lrelu(asd.w+ad.w);
  int base = rowptr[d], deg = rowptr[d+1]-base;

  // chunk 0 (j = lane): single gather of col + a_src, cached in registers
  bool v0 = lane < deg;
  int  sc = v0 ? col[base+lane] : d;
  float4 a0 = ((const float4*)a_src)[sc];
  float l0 = lrelu(a0.x+ad.x), l1 = lrelu(a0.y+ad.y);
  float l2 = lrelu(a0.z+ad.z), l3 = lrelu(a0.w+ad.w);
  const float NEG = -1e30f;
  float m0 = fmaxf(vs0, v0? l0:NEG), m1 = fmaxf(vs1, v0? l1:NEG);
  float m2 = fmaxf(vs2, v0? l2:NEG), m3 = fmaxf(vs3, v0? l3:NEG);
  for(int j0=64;j0<deg;j0+=64){            // rare: deg > 64
    int j=j0+lane;
    if(j<deg){
      int s = col[base+j];
      float4 a = ((const float4*)a_src)[s];
      m0=fmaxf(m0,lrelu(a.x+ad.x)); m1=fmaxf(m1,lrelu(a.y+ad.y));
      m2=fmaxf(m2,lrelu(a.z+ad.z)); m3=fmaxf(m3,lrelu(a.w+ad.w));
    }
  }
  m0=wmax(m0); m1=wmax(m1); m2=wmax(m2); m3=wmax(m3);

  float e0 = v0? expf(l0-m0):0.f, e1 = v0? expf(l1-m1):0.f;
  float e2 = v0? expf(l2-m2):0.f, e3 = v0? expf(l3-m3):0.f;
  float p0=e0, p1=e1, p2=e2, p3=e3;
  float t0=expf(vs0-m0), t1=expf(vs1-m1), t2=expf(vs2-m2), t3=expf(vs3-m3);

  float acc[8]={};
  int cnt = min(deg,64);
  for(int it=0; it<cnt; it+=4){
    int jj = it + q;
    float f0=__shfl(e0,jj,64), f1=__shfl(e1,jj,64);
    float f2=__shfl(e2,jj,64), f3=__shfl(e3,jj,64);
    int   sj=__shfl(sc,jj,64);
    float al = hc==0? f0 : hc==1? f1 : hc==2? f2 : f3;
    uint4 hv = *(const uint4*)(h + (size_t)sj*128 + cl*8);
    acc[0]=fmaf(al,bflo(hv.x),acc[0]); acc[1]=fmaf(al,bfhi(hv.x),acc[1]);
    acc[2]=fmaf(al,bflo(hv.y),acc[2]); acc[3]=fmaf(al,bfhi(hv.y),acc[3]);
    acc[4]=fmaf(al,bflo(hv.z),acc[4]); acc[5]=fmaf(al,bfhi(hv.z),acc[5]);
    acc[6]=fmaf(al,bflo(hv.w),acc[6]); acc[7]=fmaf(al,bfhi(hv.w),acc[7]);
  }
  for(int j0=64;j0<deg;j0+=64){            // rare: deg > 64
    int j=j0+lane;
    bool vv = j<deg;
    int  sx = vv? col[base+j] : d;
    float4 a = ((const float4*)a_src)[sx];
    float y0 = vv? expf(lrelu(a.x+ad.x)-m0):0.f;
    float y1 = vv? expf(lrelu(a.y+ad.y)-m1):0.f;
    float y2 = vv? expf(lrelu(a.z+ad.z)-m2):0.f;
    float y3 = vv? expf(lrelu(a.w+ad.w)-m3):0.f;
    p0+=y0; p1+=y1; p2+=y2; p3+=y3;
    int cc = min(deg-j0,64);
    for(int it=0; it<cc; it+=4){
      int jj = it + q;
      float f0=__shfl(y0,jj,64), f1=__shfl(y1,jj,64);
      float f2=__shfl(y2,jj,64), f3=__shfl(y3,jj,64);
      int   sj=__shfl(sx,jj,64);
      float al = hc==0? f0 : hc==1? f1 : hc==2? f2 : f3;
      uint4 hv = *(const uint4*)(h + (size_t)sj*128 + cl*8);
      acc[0]=fmaf(al,bflo(hv.x),acc[0]); acc[1]=fmaf(al,bfhi(hv.x),acc[1]);
      acc[2]=fmaf(al,bflo(hv.y),acc[2]); acc[3]=fmaf(al,bfhi(hv.y),acc[3]);
      acc[4]=fmaf(al,bflo(hv.z),acc[4]); acc[5]=fmaf(al,bfhi(hv.z),acc[5]);
      acc[6]=fmaf(al,bflo(hv.w),acc[6]); acc[7]=fmaf(al,bfhi(hv.w),acc[7]);
    }
  }
  // cross-quarter reduction: sum the 4 edge-partials per channel
  #pragma unroll
  for(int c=0;c<8;c++){
    acc[c]+=__shfl_xor(acc[c],16,64);
    acc[c]+=__shfl_xor(acc[c],32,64);
  }
  float S0=wsum(p0)+t0, S1=wsum(p1)+t1, S2=wsum(p2)+t2, S3=wsum(p3)+t3;
  float es  = hc==0? t0 : hc==1? t1 : hc==2? t2 : t3;
  float den = (hc==0? S0 : hc==1? S1 : hc==2? S2 : S3) + EPS_SM;
  // self-loop message (post-reduction: every replica adds consistently)
  uint4 hd4 = *(const uint4*)(h + (size_t)d*128 + cl*8);
  acc[0]=fmaf(es,bflo(hd4.x),acc[0]); acc[1]=fmaf(es,bfhi(hd4.x),acc[1]);
  acc[2]=fmaf(es,bflo(hd4.y),acc[2]); acc[3]=fmaf(es,bfhi(hd4.y),acc[3]);
  acc[4]=fmaf(es,bflo(hd4.z),acc[4]); acc[5]=fmaf(es,bfhi(hd4.z),acc[5]);
  acc[6]=fmaf(es,bflo(hd4.w),acc[6]); acc[7]=fmaf(es,bfhi(hd4.w),acc[7]);
  float inv = 1.f/den;

  // bias + residual + LN2 (channels replicated 4x -> /512 in reductions)
  const float* xr = xt   + (size_t)d*128 + cl*8;
  const float* bp = bias + cl*8;
  float4 xa = *(const float4*)xr, xb = *(const float4*)(xr+4);
  float4 ba = *(const float4*)bp, bb = *(const float4*)(bp+4);
  float r[8];
  r[0]=xa.x+acc[0]*inv+ba.x; r[1]=xa.y+acc[1]*inv+ba.y;
  r[2]=xa.z+acc[2]*inv+ba.z; r[3]=xa.w+acc[3]*inv+ba.w;
  r[4]=xb.x+acc[4]*inv+bb.x; r[5]=xb.y+acc[5]*inv+bb.y;
  r[6]=xb.z+acc[6]*inv+bb.z; r[7]=xb.w+acc[7]*inv+bb.w;
  float part=0;
  #pragma unroll
  for(int c=0;c<8;c++) part+=r[c];
  float mean = wsum(part)*(1.f/512.f);
  float vp=0;
  #pragma unroll
  for(int c=0;c<8;c++){ float dd=r[c]-mean; vp+=dd*dd; }
  float var = wsum(vp)*(1.f/512.f);
  float rstd = rsqrtf(var+EPS_LN);
  const float* gp = g2 + cl*8; const float* b2p = b2 + cl*8;
  float4 ga = *(const float4*)gp,  gb = *(const float4*)(gp+4);
  float4 c2a= *(const float4*)b2p, c2b= *(const float4*)(b2p+4);
  if(q==0){
    float4 o = make_float4((r[0]-mean)*rstd*ga.x+c2a.x, (r[1]-mean)*rstd*ga.y+c2a.y,
                           (r[2]-mean)*rstd*ga.z+c2a.z, (r[3]-mean)*rstd*ga.w+c2a.w);
    *(float4*)(out + (size_t)d*128 + cl*8) = o;
  }
  if(q==1){
    float4 o = make_float4((r[4]-mean)*rstd*gb.x+c2b.x, (r[5]-mean)*rstd*gb.y+c2b.y,
                           (r[6]-mean)*rstd*gb.z+c2b.z, (r[7]-mean)*rstd*gb.w+c2b.w);
    *(float4*)(out + (size_t)d*128 + cl*8 + 4) = o;
  }
}

extern "C" void kernel_launch(void* const* d_in, const int* in_sizes, int n_in,
                              void* d_out, int out_size, void* d_ws, size_t ws_size,
                              hipStream_t stream) {
  const float* x     = (const float*)d_in[0];
  const int*   ei    = (const int*)d_in[1];
  const float* W     = (const float*)d_in[4];
  const float* att_s = (const float*)d_in[5];
  const float* att_d = (const float*)d_in[6];
  const float* bias  = (const float*)d_in[7];
  const float* g1    = (const float*)d_in[8];
  const float* b1    = (const float*)d_in[9];
  const float* g2    = (const float*)d_in[10];
  const float* b2    = (const float*)d_in[11];
  int n = in_sizes[0]/128;
  int E = in_sizes[1]/2;
  float* out = (float*)d_out;

  char* ws = (char*)d_ws;
  float* xt    = (float*)ws; ws += (size_t)n*128*4;
  u16*   h     = (u16*)ws;   ws += (size_t)n*128*2;
  float* a_src = (float*)ws; ws += (size_t)n*4*4;
  float* a_dst = (float*)ws; ws += (size_t)n*4*4;
  int* deg     = (int*)ws;   ws += (size_t)n*4;
  int* rowptr  = (int*)ws;   ws += (((size_t)(n+1)*4 + 255) & ~(size_t)255);
  int* cursor  = (int*)ws;   ws += (size_t)n*4;
  int* bsum    = (int*)ws;   ws += 256;
  int* col     = (int*)ws;   ws += (size_t)E*4;

  int nb = (n + SCAN_CHUNK - 1) / SCAN_CHUNK;   // 13 for n=50000

  dim3 b256(256);
  zero_kernel   <<<(n+255)/256, b256, 0, stream>>>(deg, n);
  ln1_kernel    <<<(n+3)/4,     b256, 0, stream>>>(x, g1, b1, xt, n);
  gemm_kernel   <<<(n+31)/32,   b256, 0, stream>>>(xt, W, att_s, att_d, h, a_src, a_dst, n);
  hist_kernel   <<<(E+255)/256, b256, 0, stream>>>(ei+E, deg, E);
  scanA_kernel  <<<nb,          b256, 0, stream>>>(deg, rowptr, bsum, n);
  scanB_kernel  <<<1,           64,   0, stream>>>(bsum, rowptr, nb, n);
  scanC_kernel  <<<(n+255)/256, b256, 0, stream>>>(rowptr, bsum, cursor, n);
  scatter_kernel<<<(E+255)/256, b256, 0, stream>>>(ei, ei+E, cursor, col, E);
  agg_kernel    <<<(n+3)/4,     b256, 0, stream>>>(h, a_src, a_dst, rowptr, col, xt, bias, g2, b2, out, n);
}

// Round 8
// 258.849 us; speedup vs baseline: 1.5505x; 1.0952x over previous
//
#include <hip/hip_runtime.h>
#include <hip/hip_bf16.h>

typedef unsigned short u16;
typedef unsigned int u32;
typedef __attribute__((ext_vector_type(8))) short short8;   // 8 bf16 = 4 VGPRs
typedef __attribute__((ext_vector_type(4))) float f32x4;    // MFMA C/D frag

#define LRELU_SLOPE 0.2f
#define EPS_LN 1e-5f
#define EPS_SM 1e-16f
#define SCAN_CHUNK 4096   // 256 threads x 16 elems

__device__ __forceinline__ float bflo(u32 u){ union{u32 i; float f;} x; x.i = u<<16; return x.f; }
__device__ __forceinline__ float bfhi(u32 u){ union{u32 i; float f;} x; x.i = u & 0xffff0000u; return x.f; }
__device__ __forceinline__ float bf1(u16 u){ union{u32 i; float f;} x; x.i = ((u32)u)<<16; return x.f; }
__device__ __forceinline__ u16 f2bf(float f){
  union{float f; u32 i;} x; x.f=f; u32 i=x.i;
  u32 r = (i + 0x7fffu + ((i>>16)&1u))>>16; return (u16)r;
}
__device__ __forceinline__ u32 pack2(float a, float b){ return (u32)f2bf(a) | ((u32)f2bf(b)<<16); }
__device__ __forceinline__ float lrelu(float x){ return x > 0.f ? x : LRELU_SLOPE*x; }

__device__ __forceinline__ float wsum(float v){
  #pragma unroll
  for(int o=32;o>0;o>>=1) v += __shfl_xor(v,o,64);
  return v;
}
__device__ __forceinline__ float wmax(float v){
  #pragma unroll
  for(int o=32;o>0;o>>=1) v = fmaxf(v, __shfl_xor(v,o,64));
  return v;
}

// ---------------- LN1: xt = LayerNorm(x) (fp32 out) + deg zeroing ----------------
__global__ __launch_bounds__(256) void ln1_kernel(const float* __restrict__ x,
    const float* __restrict__ g, const float* __restrict__ b,
    float* __restrict__ xt, int* __restrict__ deg, int n){
  if(threadIdx.x < 4){ int z = blockIdx.x*4 + threadIdx.x; if(z<n) deg[z]=0; }
  int row  = blockIdx.x*4 + (threadIdx.x>>6);
  int lane = threadIdx.x & 63;
  if(row >= n) return;
  float2 xv = ((const float2*)(x + (size_t)row*128))[lane];
  float v0 = xv.x, v1 = xv.y;
  float mean = wsum(v0+v1) * (1.f/128.f);
  float d0 = v0-mean, d1 = v1-mean;
  float var = wsum(d0*d0 + d1*d1) * (1.f/128.f);
  float rstd = rsqrtf(var + EPS_LN);
  float2 gv = ((const float2*)g)[lane], bv = ((const float2*)b)[lane];
  float o0 = d0*rstd*gv.x + bv.x;
  float o1 = d1*rstd*gv.y + bv.y;
  ((float2*)(xt + (size_t)row*128))[lane] = make_float2(o0, o1);
}

// ---------------- MFMA GEMM: h = xt @ W (bf16 out) + a_src/a_dst epilogue --------
// 64-row M-tile per block (4 waves). Wave w: rows 16w..16w+15, all 128 cols.
// Wf: W in B-frag-major layout -> each B-frag is one conflict-free ds_read_b128.
// Xb: bf16 tile, row stride 136 u16 (+16B pad) -> A-frag ds_read_b128 2-way only.
__global__ __launch_bounds__(256) void gemm_kernel(const float* __restrict__ xt,
    const float* __restrict__ W, const float* __restrict__ att_src, const float* __restrict__ att_dst,
    u16* __restrict__ h, float* __restrict__ a_src, float* __restrict__ a_dst, int n){
  __shared__ u16 Wf[16384];      // 32 KB frag-major W
  __shared__ u16 Xb[64*136];     // 17 KB bf16 xt tile (pad 8 u16/row); reused for h staging
  int tid = threadIdx.x;
  int r0  = blockIdx.x*64;

  // stage W -> Wf: element W[k][n] at idx ((tile*4+ks)*64 + q*16 + c)*8 + j
  //   tile=n>>4, c=n&15, ks=k>>5, q=(k>>3)&3, j=k&7. Pack (k even, k+1) pairs as u32.
  const float4* W4 = (const float4*)W;
  for(int p=tid; p<2048; p+=256){
    int g = p & 31, kk = p >> 5;
    int k0 = kk*2, n0 = g*4;
    float4 w0 = W4[k0*32 + g];
    float4 w1 = W4[(k0+1)*32 + g];
    int ks = k0>>5, q = (k0>>3)&3, j = k0&7;   // j even
    float e0[4] = {w0.x,w0.y,w0.z,w0.w};
    float e1[4] = {w1.x,w1.y,w1.z,w1.w};
    #pragma unroll
    for(int u=0;u<4;u++){
      int nn = n0+u;
      int idx = (((nn>>4)*4 + ks)*64 + q*16 + (nn&15))*8 + j;
      ((u32*)Wf)[idx>>1] = pack2(e0[u], e1[u]);
    }
  }
  // stage xt tile -> bf16 Xb
  const float4* X4 = (const float4*)xt;
  for(int i=tid; i<2048; i+=256){
    int row = i>>5, cg = i&31, col = cg*4;
    int gr = r0+row;
    float4 v = (gr<n) ? X4[(size_t)gr*32 + cg] : make_float4(0,0,0,0);
    *(uint2*)&Xb[row*136 + col] = make_uint2(pack2(v.x,v.y), pack2(v.z,v.w));
  }
  __syncthreads();

  int w = tid>>6, lane = tid&63;
  int slab = w*16, c = lane&15, q = lane>>4;
  f32x4 acc[8];
  #pragma unroll
  for(int t=0;t<8;t++) acc[t] = (f32x4){0.f,0.f,0.f,0.f};
  #pragma unroll
  for(int ks=0;ks<4;ks++){
    short8 A = *(const short8*)&Xb[(slab + c)*136 + ks*32 + q*8];
    #pragma unroll
    for(int t=0;t<8;t++){
      short8 B = *(const short8*)&Wf[((t*4+ks)*64 + lane)*8];
      acc[t] = __builtin_amdgcn_mfma_f32_16x16x32_bf16(A, B, acc[t], 0, 0, 0);
    }
  }
  __syncthreads();   // all waves done reading Xb
  // D-frags -> Xb as bf16 h tile. C/D layout: col=lane&15, row=q*4+reg.
  #pragma unroll
  for(int t=0;t<8;t++){
    #pragma unroll
    for(int r=0;r<4;r++){
      Xb[(slab + q*4 + r)*136 + t*16 + c] = f2bf(acc[t][r]);
    }
  }
  __syncthreads();
  // coalesced h write + logits; thread p -> row p>>2, quarter qt (64B = 4x uint4)
  {
    int row = tid>>2, qt = tid&3;
    int gr = r0+row;
    if(gr<n){
      const uint4* src = (const uint4*)((const char*)Xb + row*272 + qt*64);
      uint4* dst = (uint4*)((char*)(h + (size_t)gr*128) + qt*64);
      dst[0] = src[0];
      dst[1] = src[1];
      dst[2] = src[2];
      dst[3] = src[3];
    }
    int hd = qt;
    if(gr<n){
      float as=0.f, ad=0.f;
      const u16* hp = &Xb[row*136 + hd*32];
      #pragma unroll
      for(int sgm=0;sgm<4;sgm++){
        #pragma unroll
        for(int e=0;e<8;e++){
          float v = bf1(hp[sgm*8+e]);
          as = fmaf(v, att_src[hd*32+sgm*8+e], as);
          ad = fmaf(v, att_dst[hd*32+sgm*8+e], ad);
        }
      }
      a_src[(size_t)gr*4+hd] = as;
      a_dst[(size_t)gr*4+hd] = ad;
    }
  }
}

// ---------------- CSR build ----------------
__global__ void hist_kernel(const int* __restrict__ dst, int* __restrict__ deg, int E){
  int e = blockIdx.x*blockDim.x + threadIdx.x; if(e<E) atomicAdd(&deg[dst[e]],1);
}
__global__ __launch_bounds__(256) void scanA_kernel(const int* __restrict__ deg,
    int* __restrict__ rowptr, int* __restrict__ bsum, int n){
  __shared__ int part[256];
  int tid = threadIdx.x;
  int base = blockIdx.x*SCAN_CHUNK + tid*16;
  int v[16]; int s=0;
  #pragma unroll
  for(int i=0;i<16;i++){ int idx=base+i; int xv=(idx<n)? deg[idx]:0; v[i]=s; s+=xv; }
  part[tid]=s; __syncthreads();
  int mys=s;
  for(int off=1;off<256;off<<=1){
    int t = (tid>=off)? part[tid-off] : 0;
    __syncthreads(); part[tid]+=t; __syncthreads();
  }
  int run = part[tid]-mys;
  #pragma unroll
  for(int i=0;i<16;i++){ int idx=base+i; if(idx<n) rowptr[idx]=v[i]+run; }
  if(tid==255) bsum[blockIdx.x]=part[255];
}
__global__ __launch_bounds__(64) void scanB_kernel(int* __restrict__ bsum,
    int* __restrict__ rowptr, int nb, int n){
  int lane = threadIdx.x;
  int v = (lane<nb)? bsum[lane] : 0;
  int inc = v;
  #pragma unroll
  for(int o=1;o<64;o<<=1){ int t=__shfl_up(inc,o,64); if(lane>=o) inc+=t; }
  if(lane<nb) bsum[lane] = inc - v;
  if(lane==63) rowptr[n] = inc;
}
__global__ __launch_bounds__(256) void scanC_kernel(int* __restrict__ rowptr,
    const int* __restrict__ bsum, int* __restrict__ cursor, int n){
  int idx = blockIdx.x*blockDim.x + threadIdx.x;
  if(idx<n){ int v = rowptr[idx] + bsum[idx/SCAN_CHUNK]; rowptr[idx]=v; cursor[idx]=v; }
}
__global__ void scatter_kernel(const int* __restrict__ src, const int* __restrict__ dst,
    int* __restrict__ cursor, int* __restrict__ col, int E){
  int e = blockIdx.x*blockDim.x + threadIdx.x;
  if(e<E){ int d=dst[e]; int pos=atomicAdd(&cursor[d],1); col[pos]=src[e]; }
}

// ---------------- Aggregation: softmax + gather + bias + residual + LN2 ----------------
// One wave per dst. cl=lane&15 owns 8 channels (dwordx4 of bf16 h, head hc=cl>>2);
// q=lane>>4 owns edge it*4+q -> 4 edges per iteration, 1KB/wave gather instr.
__global__ __launch_bounds__(256) void agg_kernel(const u16* __restrict__ h,
    const float* __restrict__ a_src, const float* __restrict__ a_dst,
    const int* __restrict__ rowptr, const int* __restrict__ col,
    const float* __restrict__ xt, const float* __restrict__ bias,
    const float* __restrict__ g2, const float* __restrict__ b2,
    float* __restrict__ out, int n){
  int d    = blockIdx.x*4 + (threadIdx.x>>6);
  int lane = threadIdx.x & 63;
  if(d >= n) return;
  int q = lane>>4, cl = lane&15, hc = cl>>2;   // head of channels 8*cl..8*cl+7
  float4 ad  = ((const float4*)a_dst)[d];
  float4 asd = ((const float4*)a_src)[d];
  float vs0 = lrelu(asd.x+ad.x), vs1 = lrelu(asd.y+ad.y);
  float vs2 = lrelu(asd.z+ad.z), vs3 = lrelu(asd.w+ad.w);
  int base = rowptr[d], deg = rowptr[d+1]-base;

  bool v0 = lane < deg;
  int  sc = v0 ? col[base+lane] : d;
  float4 a0 = ((const float4*)a_src)[sc];
  float l0 = lrelu(a0.x+ad.x), l1 = lrelu(a0.y+ad.y);
  float l2 = lrelu(a0.z+ad.z), l3 = lrelu(a0.w+ad.w);
  const float NEG = -1e30f;
  float m0 = fmaxf(vs0, v0? l0:NEG), m1 = fmaxf(vs1, v0? l1:NEG);
  float m2 = fmaxf(vs2, v0? l2:NEG), m3 = fmaxf(vs3, v0? l3:NEG);
  for(int j0=64;j0<deg;j0+=64){
    int j=j0+lane;
    if(j<deg){
      int s = col[base+j];
      float4 a = ((const float4*)a_src)[s];
      m0=fmaxf(m0,lrelu(a.x+ad.x)); m1=fmaxf(m1,lrelu(a.y+ad.y));
      m2=fmaxf(m2,lrelu(a.z+ad.z)); m3=fmaxf(m3,lrelu(a.w+ad.w));
    }
  }
  m0=wmax(m0); m1=wmax(m1); m2=wmax(m2); m3=wmax(m3);

  float e0 = v0? expf(l0-m0):0.f, e1 = v0? expf(l1-m1):0.f;
  float e2 = v0? expf(l2-m2):0.f, e3 = v0? expf(l3-m3):0.f;
  float p0=e0, p1=e1, p2=e2, p3=e3;
  float t0=expf(vs0-m0), t1=expf(vs1-m1), t2=expf(vs2-m2), t3=expf(vs3-m3);

  float acc[8]={};
  int cnt = min(deg,64);
  for(int it=0; it<cnt; it+=4){
    int jj = it + q;
    float f0=__shfl(e0,jj,64), f1=__shfl(e1,jj,64);
    float f2=__shfl(e2,jj,64), f3=__shfl(e3,jj,64);
    int   sj=__shfl(sc,jj,64);
    float al = hc==0? f0 : hc==1? f1 : hc==2? f2 : f3;
    uint4 hv = *(const uint4*)(h + (size_t)sj*128 + cl*8);
    acc[0]=fmaf(al,bflo(hv.x),acc[0]); acc[1]=fmaf(al,bfhi(hv.x),acc[1]);
    acc[2]=fmaf(al,bflo(hv.y),acc[2]); acc[3]=fmaf(al,bfhi(hv.y),acc[3]);
    acc[4]=fmaf(al,bflo(hv.z),acc[4]); acc[5]=fmaf(al,bfhi(hv.z),acc[5]);
    acc[6]=fmaf(al,bflo(hv.w),acc[6]); acc[7]=fmaf(al,bfhi(hv.w),acc[7]);
  }
  for(int j0=64;j0<deg;j0+=64){
    int j=j0+lane;
    bool vv = j<deg;
    int  sx = vv? col[base+j] : d;
    float4 a = ((const float4*)a_src)[sx];
    float y0 = vv? expf(lrelu(a.x+ad.x)-m0):0.f;
    float y1 = vv? expf(lrelu(a.y+ad.y)-m1):0.f;
    float y2 = vv? expf(lrelu(a.z+ad.z)-m2):0.f;
    float y3 = vv? expf(lrelu(a.w+ad.w)-m3):0.f;
    p0+=y0; p1+=y1; p2+=y2; p3+=y3;
    int cc = min(deg-j0,64);
    for(int it=0; it<cc; it+=4){
      int jj = it + q;
      float f0=__shfl(y0,jj,64), f1=__shfl(y1,jj,64);
      float f2=__shfl(y2,jj,64), f3=__shfl(y3,jj,64);
      int   sj=__shfl(sx,jj,64);
      float al = hc==0? f0 : hc==1? f1 : hc==2? f2 : f3;
      uint4 hv = *(const uint4*)(h + (size_t)sj*128 + cl*8);
      acc[0]=fmaf(al,bflo(hv.x),acc[0]); acc[1]=fmaf(al,bfhi(hv.x),acc[1]);
      acc[2]=fmaf(al,bflo(hv.y),acc[2]); acc[3]=fmaf(al,bfhi(hv.y),acc[3]);
      acc[4]=fmaf(al,bflo(hv.z),acc[4]); acc[5]=fmaf(al,bfhi(hv.z),acc[5]);
      acc[6]=fmaf(al,bflo(hv.w),acc[6]); acc[7]=fmaf(al,bfhi(hv.w),acc[7]);
    }
  }
  #pragma unroll
  for(int c=0;c<8;c++){
    acc[c]+=__shfl_xor(acc[c],16,64);
    acc[c]+=__shfl_xor(acc[c],32,64);
  }
  float S0=wsum(p0)+t0, S1=wsum(p1)+t1, S2=wsum(p2)+t2, S3=wsum(p3)+t3;
  float es  = hc==0? t0 : hc==1? t1 : hc==2? t2 : t3;
  float den = (hc==0? S0 : hc==1? S1 : hc==2? S2 : S3) + EPS_SM;
  uint4 hd4 = *(const uint4*)(h + (size_t)d*128 + cl*8);
  acc[0]=fmaf(es,bflo(hd4.x),acc[0]); acc[1]=fmaf(es,bfhi(hd4.x),acc[1]);
  acc[2]=fmaf(es,bflo(hd4.y),acc[2]); acc[3]=fmaf(es,bfhi(hd4.y),acc[3]);
  acc[4]=fmaf(es,bflo(hd4.z),acc[4]); acc[5]=fmaf(es,bfhi(hd4.z),acc[5]);
  acc[6]=fmaf(es,bflo(hd4.w),acc[6]); acc[7]=fmaf(es,bfhi(hd4.w),acc[7]);
  float inv = 1.f/den;

  const float* xr = xt   + (size_t)d*128 + cl*8;
  const float* bp = bias + cl*8;
  float4 xa = *(const float4*)xr, xb = *(const float4*)(xr+4);
  float4 ba = *(const float4*)bp, bb = *(const float4*)(bp+4);
  float r[8];
  r[0]=xa.x+acc[0]*inv+ba.x; r[1]=xa.y+acc[1]*inv+ba.y;
  r[2]=xa.z+acc[2]*inv+ba.z; r[3]=xa.w+acc[3]*inv+ba.w;
  r[4]=xb.x+acc[4]*inv+bb.x; r[5]=xb.y+acc[5]*inv+bb.y;
  r[6]=xb.z+acc[6]*inv+bb.z; r[7]=xb.w+acc[7]*inv+bb.w;
  float part=0;
  #pragma unroll
  for(int c=0;c<8;c++) part+=r[c];
  float mean = wsum(part)*(1.f/512.f);
  float vp=0;
  #pragma unroll
  for(int c=0;c<8;c++){ float dd=r[c]-mean; vp+=dd*dd; }
  float var = wsum(vp)*(1.f/512.f);
  float rstd = rsqrtf(var+EPS_LN);
  const float* gp = g2 + cl*8; const float* b2p = b2 + cl*8;
  float4 ga = *(const float4*)gp,  gb = *(const float4*)(gp+4);
  float4 c2a= *(const float4*)b2p, c2b= *(const float4*)(b2p+4);
  if(q==0){
    float4 o = make_float4((r[0]-mean)*rstd*ga.x+c2a.x, (r[1]-mean)*rstd*ga.y+c2a.y,
                           (r[2]-mean)*rstd*ga.z+c2a.z, (r[3]-mean)*rstd*ga.w+c2a.w);
    *(float4*)(out + (size_t)d*128 + cl*8) = o;
  }
  if(q==1){
    float4 o = make_float4((r[4]-mean)*rstd*gb.x+c2b.x, (r[5]-mean)*rstd*gb.y+c2b.y,
                           (r[6]-mean)*rstd*gb.z+c2b.z, (r[7]-mean)*rstd*gb.w+c2b.w);
    *(float4*)(out + (size_t)d*128 + cl*8 + 4) = o;
  }
}

extern "C" void kernel_launch(void* const* d_in, const int* in_sizes, int n_in,
                              void* d_out, int out_size, void* d_ws, size_t ws_size,
                              hipStream_t stream) {
  const float* x     = (const float*)d_in[0];
  const int*   ei    = (const int*)d_in[1];
  const float* W     = (const float*)d_in[4];
  const float* att_s = (const float*)d_in[5];
  const float* att_d = (const float*)d_in[6];
  const float* bias  = (const float*)d_in[7];
  const float* g1    = (const float*)d_in[8];
  const float* b1    = (const float*)d_in[9];
  const float* g2    = (const float*)d_in[10];
  const float* b2    = (const float*)d_in[11];
  int n = in_sizes[0]/128;
  int E = in_sizes[1]/2;
  float* out = (float*)d_out;

  char* ws = (char*)d_ws;
  float* xt    = (float*)ws; ws += (size_t)n*128*4;
  u16*   h     = (u16*)ws;   ws += (size_t)n*128*2;
  float* a_src = (float*)ws; ws += (size_t)n*4*4;
  float* a_dst = (float*)ws; ws += (size_t)n*4*4;
  int* deg     = (int*)ws;   ws += (size_t)n*4;
  int* rowptr  = (int*)ws;   ws += (((size_t)(n+1)*4 + 255) & ~(size_t)255);
  int* cursor  = (int*)ws;   ws += (size_t)n*4;
  int* bsum    = (int*)ws;   ws += 256;
  int* col     = (int*)ws;   ws += (size_t)E*4;

  int nb = (n + SCAN_CHUNK - 1) / SCAN_CHUNK;   // 13 for n=50000

  dim3 b256(256);
  ln1_kernel    <<<(n+3)/4,     b256, 0, stream>>>(x, g1, b1, xt, deg, n);
  gemm_kernel   <<<(n+63)/64,   b256, 0, stream>>>(xt, W, att_s, att_d, h, a_src, a_dst, n);
  hist_kernel   <<<(E+255)/256, b256, 0, stream>>>(ei+E, deg, E);
  scanA_kernel  <<<nb,          b256, 0, stream>>>(deg, rowptr, bsum, n);
  scanB_kernel  <<<1,           64,   0, stream>>>(bsum, rowptr, nb, n);
  scanC_kernel  <<<(n+255)/256, b256, 0, stream>>>(rowptr, bsum, cursor, n);
  scatter_kernel<<<(E+255)/256, b256, 0, stream>>>(ei, ei+E, cursor, col, E);
  agg_kernel    <<<(n+3)/4,     b256, 0, stream>>>(h, a_src, a_dst, rowptr, col, xt, bias, g2, b2, out, n);
}

// Round 9
// 239.915 us; speedup vs baseline: 1.6729x; 1.0789x over previous
//
#include <hip/hip_runtime.h>
#include <hip/hip_bf16.h>

typedef unsigned short u16;
typedef unsigned int u32;
typedef __attribute__((ext_vector_type(8))) short short8;   // 8 bf16 = 4 VGPRs
typedef __attribute__((ext_vector_type(4))) float f32x4;    // MFMA C/D frag

#define LRELU_SLOPE 0.2f
#define EPS_LN 1e-5f
#define EPS_SM 1e-16f
#define SCAN_CHUNK 4096   // 256 threads x 16 elems; chunk id = idx>>12

__device__ __forceinline__ float bflo(u32 u){ union{u32 i; float f;} x; x.i = u<<16; return x.f; }
__device__ __forceinline__ float bfhi(u32 u){ union{u32 i; float f;} x; x.i = u & 0xffff0000u; return x.f; }
__device__ __forceinline__ float bf1(u16 u){ union{u32 i; float f;} x; x.i = ((u32)u)<<16; return x.f; }
__device__ __forceinline__ u16 f2bf(float f){
  union{float f; u32 i;} x; x.f=f; u32 i=x.i;
  u32 r = (i + 0x7fffu + ((i>>16)&1u))>>16; return (u16)r;
}
__device__ __forceinline__ u32 pack2(float a, float b){ return (u32)f2bf(a) | ((u32)f2bf(b)<<16); }
__device__ __forceinline__ float lrelu(float x){ return x > 0.f ? x : LRELU_SLOPE*x; }

__device__ __forceinline__ float wsum(float v){
  #pragma unroll
  for(int o=32;o>0;o>>=1) v += __shfl_xor(v,o,64);
  return v;
}

// ---------------- LN1: xt = LayerNorm(x) (bf16 out) + deg zeroing ----------------
__global__ __launch_bounds__(256) void ln1_kernel(const float* __restrict__ x,
    const float* __restrict__ g, const float* __restrict__ b,
    u16* __restrict__ xt, int* __restrict__ deg, int n){
  if(threadIdx.x < 4){ int z = blockIdx.x*4 + threadIdx.x; if(z<n) deg[z]=0; }
  int row  = blockIdx.x*4 + (threadIdx.x>>6);
  int lane = threadIdx.x & 63;
  if(row >= n) return;
  float2 xv = ((const float2*)(x + (size_t)row*128))[lane];
  float v0 = xv.x, v1 = xv.y;
  float mean = wsum(v0+v1) * (1.f/128.f);
  float d0 = v0-mean, d1 = v1-mean;
  float var = wsum(d0*d0 + d1*d1) * (1.f/128.f);
  float rstd = rsqrtf(var + EPS_LN);
  float2 gv = ((const float2*)g)[lane], bv = ((const float2*)b)[lane];
  float o0 = d0*rstd*gv.x + bv.x;
  float o1 = d1*rstd*gv.y + bv.y;
  ((u32*)(xt + (size_t)row*128))[lane] = pack2(o0, o1);
}

// ---------------- MFMA GEMM: h = xt @ W (bf16) + logits + fused edge histogram ----
__global__ __launch_bounds__(256) void gemm_kernel(const u16* __restrict__ xt,
    const float* __restrict__ W, const float* __restrict__ att_src, const float* __restrict__ att_dst,
    u16* __restrict__ h, float* __restrict__ a_src, float* __restrict__ a_dst,
    const int* __restrict__ edst, int* __restrict__ deg, int E, int n){
  __shared__ u16 Wf[16384];      // 32 KB frag-major W
  __shared__ u16 Xb[64*136];     // 17 KB bf16 xt tile (pad 8 u16/row); reused for h staging
  int tid = threadIdx.x;
  int r0  = blockIdx.x*64;

  // fused histogram (deg zeroed by ln1 in previous dispatch)
  for(int e = blockIdx.x*256 + tid; e < E; e += gridDim.x*256)
    atomicAdd(&deg[edst[e]], 1);

  // stage W -> Wf: element W[k][n] at idx ((tile*4+ks)*64 + q*16 + c)*8 + j
  const float4* W4 = (const float4*)W;
  for(int p=tid; p<2048; p+=256){
    int g = p & 31, kk = p >> 5;
    int k0 = kk*2, n0 = g*4;
    float4 w0 = W4[k0*32 + g];
    float4 w1 = W4[(k0+1)*32 + g];
    int ks = k0>>5, q = (k0>>3)&3, j = k0&7;   // j even
    float e0[4] = {w0.x,w0.y,w0.z,w0.w};
    float e1[4] = {w1.x,w1.y,w1.z,w1.w};
    #pragma unroll
    for(int u=0;u<4;u++){
      int nn = n0+u;
      int idx = (((nn>>4)*4 + ks)*64 + q*16 + (nn&15))*8 + j;
      ((u32*)Wf)[idx>>1] = pack2(e0[u], e1[u]);
    }
  }
  // stage bf16 xt tile -> Xb (straight 16B copies)
  for(int i=tid; i<1024; i+=256){
    int row = i>>4, seg = i&15;
    int gr = r0+row;
    uint4 v = (gr<n) ? ((const uint4*)(xt + (size_t)gr*128))[seg] : make_uint4(0,0,0,0);
    *(uint4*)&Xb[row*136 + seg*8] = v;
  }
  __syncthreads();

  int w = tid>>6, lane = tid&63;
  int slab = w*16, c = lane&15, q = lane>>4;
  f32x4 acc[8];
  #pragma unroll
  for(int t=0;t<8;t++) acc[t] = (f32x4){0.f,0.f,0.f,0.f};
  #pragma unroll
  for(int ks=0;ks<4;ks++){
    short8 A = *(const short8*)&Xb[(slab + c)*136 + ks*32 + q*8];
    #pragma unroll
    for(int t=0;t<8;t++){
      short8 B = *(const short8*)&Wf[((t*4+ks)*64 + lane)*8];
      acc[t] = __builtin_amdgcn_mfma_f32_16x16x32_bf16(A, B, acc[t], 0, 0, 0);
    }
  }
  __syncthreads();   // all waves done reading Xb
  // D-frags -> Xb as bf16 h tile. C/D layout: col=lane&15, row=q*4+reg.
  #pragma unroll
  for(int t=0;t<8;t++){
    #pragma unroll
    for(int r=0;r<4;r++){
      Xb[(slab + q*4 + r)*136 + t*16 + c] = f2bf(acc[t][r]);
    }
  }
  __syncthreads();
  // coalesced h write + logits; thread p -> row p>>2, quarter qt (64B = 4x uint4)
  {
    int row = tid>>2, qt = tid&3;
    int gr = r0+row;
    if(gr<n){
      const uint4* src = (const uint4*)((const char*)Xb + row*272 + qt*64);
      uint4* dst = (uint4*)((char*)(h + (size_t)gr*128) + qt*64);
      dst[0] = src[0];
      dst[1] = src[1];
      dst[2] = src[2];
      dst[3] = src[3];
    }
    int hd = qt;
    if(gr<n){
      float as=0.f, ad=0.f;
      const u16* hp = &Xb[row*136 + hd*32];
      #pragma unroll
      for(int sgm=0;sgm<4;sgm++){
        #pragma unroll
        for(int e=0;e<8;e++){
          float v = bf1(hp[sgm*8+e]);
          as = fmaf(v, att_src[hd*32+sgm*8+e], as);
          ad = fmaf(v, att_dst[hd*32+sgm*8+e], ad);
        }
      }
      a_src[(size_t)gr*4+hd] = as;
      a_dst[(size_t)gr*4+hd] = ad;
    }
  }
}

// ---------------- CSR build (2-level: chunk-local prefixes + bsum offsets) --------
// scanA: rowptr[idx] (idx<=n) and cursor[idx] (idx<n) get CHUNK-LOCAL prefixes.
__global__ __launch_bounds__(256) void scanA_kernel(const int* __restrict__ deg,
    int* __restrict__ rowptr, int* __restrict__ cursor, int* __restrict__ bsum, int n){
  __shared__ int part[256];
  int tid = threadIdx.x;
  int base = blockIdx.x*SCAN_CHUNK + tid*16;
  int v[16]; int s=0;
  #pragma unroll
  for(int i=0;i<16;i++){ int idx=base+i; int xv=(idx<n)? deg[idx]:0; v[i]=s; s+=xv; }
  part[tid]=s; __syncthreads();
  int mys=s;
  for(int off=1;off<256;off<<=1){
    int t = (tid>=off)? part[tid-off] : 0;
    __syncthreads(); part[tid]+=t; __syncthreads();
  }
  int run = part[tid]-mys;
  #pragma unroll
  for(int i=0;i<16;i++){
    int idx=base+i;
    if(idx<=n) rowptr[idx]=v[i]+run;
    if(idx<n)  cursor[idx]=v[i]+run;
  }
  if(tid==255) bsum[blockIdx.x]=part[255];
}
// scanB: in-place exclusive scan of chunk totals (nb <= 64).
__global__ __launch_bounds__(64) void scanB_kernel(int* __restrict__ bsum, int nb){
  int lane = threadIdx.x;
  int v = (lane<nb)? bsum[lane] : 0;
  int inc = v;
  #pragma unroll
  for(int o=1;o<64;o<<=1){ int t=__shfl_up(inc,o,64); if(lane>=o) inc+=t; }
  if(lane<nb) bsum[lane] = inc - v;
}
__global__ void scatter_kernel(const int* __restrict__ src, const int* __restrict__ dst,
    int* __restrict__ cursor, const int* __restrict__ bsum, int* __restrict__ col, int E){
  int e = blockIdx.x*blockDim.x + threadIdx.x;
  if(e<E){
    int d=dst[e];
    int pos = bsum[d>>12] + atomicAdd(&cursor[d],1);
    col[pos]=src[e];
  }
}

// ---------------- Aggregation: softmax (no max pass) + gather + residual + LN2 ----
// One wave per dst. cl=lane&15 owns 8 channels (dwordx4 of bf16 h, head hc=cl>>2);
// q=lane>>4 owns edge it*4+q -> 4 edges per iteration, 1KB/wave gather instr.
// Softmax shift-invariance: no max subtraction (logits ~<10, clamp 60 for safety).
__global__ __launch_bounds__(256) void agg_kernel(const u16* __restrict__ h,
    const float* __restrict__ a_src, const float* __restrict__ a_dst,
    const int* __restrict__ rowptr, const int* __restrict__ bsum, const int* __restrict__ col,
    const u16* __restrict__ xt, const float* __restrict__ bias,
    const float* __restrict__ g2, const float* __restrict__ b2,
    float* __restrict__ out, int n){
  int d    = blockIdx.x*4 + (threadIdx.x>>6);
  int lane = threadIdx.x & 63;
  if(d >= n) return;
  int q = lane>>4, cl = lane&15, hc = cl>>2;   // head of channels 8*cl..8*cl+7
  float4 ad  = ((const float4*)a_dst)[d];
  float4 asd = ((const float4*)a_src)[d];
  float t0 = expf(fminf(lrelu(asd.x+ad.x),60.f));
  float t1 = expf(fminf(lrelu(asd.y+ad.y),60.f));
  float t2 = expf(fminf(lrelu(asd.z+ad.z),60.f));
  float t3 = expf(fminf(lrelu(asd.w+ad.w),60.f));
  int base = rowptr[d]   + bsum[d>>12];
  int d1   = d+1;
  int end  = rowptr[d1]  + bsum[d1>>12];
  int deg  = end - base;

  float p0=0.f,p1=0.f,p2=0.f,p3=0.f;
  float acc[8]={};
  for(int j0=0;j0<deg;j0+=64){
    int j=j0+lane;
    bool vv = j<deg;
    int  sx = vv? col[base+j] : 0;
    float4 a = ((const float4*)a_src)[sx];
    float y0 = vv? expf(fminf(lrelu(a.x+ad.x),60.f)) : 0.f;
    float y1 = vv? expf(fminf(lrelu(a.y+ad.y),60.f)) : 0.f;
    float y2 = vv? expf(fminf(lrelu(a.z+ad.z),60.f)) : 0.f;
    float y3 = vv? expf(fminf(lrelu(a.w+ad.w),60.f)) : 0.f;
    p0+=y0; p1+=y1; p2+=y2; p3+=y3;
    int cc = min(deg-j0,64);
    for(int it=0; it<cc; it+=4){
      int jj = it + q;
      float f0=__shfl(y0,jj,64), f1=__shfl(y1,jj,64);
      float f2=__shfl(y2,jj,64), f3=__shfl(y3,jj,64);
      int   sj=__shfl(sx,jj,64);
      float al = hc==0? f0 : hc==1? f1 : hc==2? f2 : f3;
      uint4 hv = *(const uint4*)(h + (size_t)sj*128 + cl*8);
      acc[0]=fmaf(al,bflo(hv.x),acc[0]); acc[1]=fmaf(al,bfhi(hv.x),acc[1]);
      acc[2]=fmaf(al,bflo(hv.y),acc[2]); acc[3]=fmaf(al,bfhi(hv.y),acc[3]);
      acc[4]=fmaf(al,bflo(hv.z),acc[4]); acc[5]=fmaf(al,bfhi(hv.z),acc[5]);
      acc[6]=fmaf(al,bflo(hv.w),acc[6]); acc[7]=fmaf(al,bfhi(hv.w),acc[7]);
    }
  }
  // cross-quarter reduction: sum the 4 edge-partials per channel
  #pragma unroll
  for(int c=0;c<8;c++){
    acc[c]+=__shfl_xor(acc[c],16,64);
    acc[c]+=__shfl_xor(acc[c],32,64);
  }
  float S0=wsum(p0)+t0, S1=wsum(p1)+t1, S2=wsum(p2)+t2, S3=wsum(p3)+t3;
  float es  = hc==0? t0 : hc==1? t1 : hc==2? t2 : t3;
  float den = (hc==0? S0 : hc==1? S1 : hc==2? S2 : S3) + EPS_SM;
  // self-loop message (post-reduction: every replica adds consistently)
  uint4 hd4 = *(const uint4*)(h + (size_t)d*128 + cl*8);
  acc[0]=fmaf(es,bflo(hd4.x),acc[0]); acc[1]=fmaf(es,bfhi(hd4.x),acc[1]);
  acc[2]=fmaf(es,bflo(hd4.y),acc[2]); acc[3]=fmaf(es,bfhi(hd4.y),acc[3]);
  acc[4]=fmaf(es,bflo(hd4.z),acc[4]); acc[5]=fmaf(es,bfhi(hd4.z),acc[5]);
  acc[6]=fmaf(es,bflo(hd4.w),acc[6]); acc[7]=fmaf(es,bfhi(hd4.w),acc[7]);
  float inv = 1.f/den;

  // bias + residual (bf16 xt) + LN2 (channels replicated 4x -> /512 in reductions)
  uint4 xv4 = *(const uint4*)(xt + (size_t)d*128 + cl*8);
  const float* bp = bias + cl*8;
  float4 ba = *(const float4*)bp, bb = *(const float4*)(bp+4);
  float r[8];
  r[0]=bflo(xv4.x)+acc[0]*inv+ba.x; r[1]=bfhi(xv4.x)+acc[1]*inv+ba.y;
  r[2]=bflo(xv4.y)+acc[2]*inv+ba.z; r[3]=bfhi(xv4.y)+acc[3]*inv+ba.w;
  r[4]=bflo(xv4.z)+acc[4]*inv+bb.x; r[5]=bfhi(xv4.z)+acc[5]*inv+bb.y;
  r[6]=bflo(xv4.w)+acc[6]*inv+bb.z; r[7]=bfhi(xv4.w)+acc[7]*inv+bb.w;
  float part=0;
  #pragma unroll
  for(int c=0;c<8;c++) part+=r[c];
  float mean = wsum(part)*(1.f/512.f);
  float vp=0;
  #pragma unroll
  for(int c=0;c<8;c++){ float dd=r[c]-mean; vp+=dd*dd; }
  float var = wsum(vp)*(1.f/512.f);
  float rstd = rsqrtf(var+EPS_LN);
  const float* gp = g2 + cl*8; const float* b2p = b2 + cl*8;
  float4 ga = *(const float4*)gp,  gb = *(const float4*)(gp+4);
  float4 c2a= *(const float4*)b2p, c2b= *(const float4*)(b2p+4);
  if(q==0){
    float4 o = make_float4((r[0]-mean)*rstd*ga.x+c2a.x, (r[1]-mean)*rstd*ga.y+c2a.y,
                           (r[2]-mean)*rstd*ga.z+c2a.z, (r[3]-mean)*rstd*ga.w+c2a.w);
    *(float4*)(out + (size_t)d*128 + cl*8) = o;
  }
  if(q==1){
    float4 o = make_float4((r[4]-mean)*rstd*gb.x+c2b.x, (r[5]-mean)*rstd*gb.y+c2b.y,
                           (r[6]-mean)*rstd*gb.z+c2b.z, (r[7]-mean)*rstd*gb.w+c2b.w);
    *(float4*)(out + (size_t)d*128 + cl*8 + 4) = o;
  }
}

extern "C" void kernel_launch(void* const* d_in, const int* in_sizes, int n_in,
                              void* d_out, int out_size, void* d_ws, size_t ws_size,
                              hipStream_t stream) {
  const float* x     = (const float*)d_in[0];
  const int*   ei    = (const int*)d_in[1];
  const float* W     = (const float*)d_in[4];
  const float* att_s = (const float*)d_in[5];
  const float* att_d = (const float*)d_in[6];
  const float* bias  = (const float*)d_in[7];
  const float* g1    = (const float*)d_in[8];
  const float* b1    = (const float*)d_in[9];
  const float* g2    = (const float*)d_in[10];
  const float* b2    = (const float*)d_in[11];
  int n = in_sizes[0]/128;
  int E = in_sizes[1]/2;
  float* out = (float*)d_out;

  char* ws = (char*)d_ws;
  u16*   xt    = (u16*)ws;   ws += (size_t)n*128*2;
  u16*   h     = (u16*)ws;   ws += (size_t)n*128*2;
  float* a_src = (float*)ws; ws += (size_t)n*4*4;
  float* a_dst = (float*)ws; ws += (size_t)n*4*4;
  int* deg     = (int*)ws;   ws += (size_t)n*4;
  int* rowptr  = (int*)ws;   ws += (((size_t)(n+1)*4 + 255) & ~(size_t)255);
  int* cursor  = (int*)ws;   ws += (size_t)n*4;
  int* bsum    = (int*)ws;   ws += 256;
  int* col     = (int*)ws;   ws += (size_t)E*4;

  int nb = n/SCAN_CHUNK + 1;   // guarantees idx=n falls inside chunk nb-1

  dim3 b256(256);
  ln1_kernel    <<<(n+3)/4,     b256, 0, stream>>>(x, g1, b1, xt, deg, n);
  gemm_kernel   <<<(n+63)/64,   b256, 0, stream>>>(xt, W, att_s, att_d, h, a_src, a_dst, ei+E, deg, E, n);
  scanA_kernel  <<<nb,          b256, 0, stream>>>(deg, rowptr, cursor, bsum, n);
  scanB_kernel  <<<1,           64,   0, stream>>>(bsum, nb);
  scatter_kernel<<<(E+255)/256, b256, 0, stream>>>(ei, ei+E, cursor, bsum, col, E);
  agg_kernel    <<<(n+3)/4,     b256, 0, stream>>>(h, a_src, a_dst, rowptr, bsum, col, xt, bias, g2, b2, out, n);
}